// Round 13
// baseline (116.236 us; speedup 1.0000x reference)
//
#include <hip/hip_runtime.h>

// UniformBottomUpHTMM: T=64 trees, depth 10 (N1=2047 heap), C=16, M=64,
// G=16. r24: de-serialize the leaf phase. r23 (linearity fold) = 51.3us,
// VGPR=92, zero spill -- champion. Busy 11.5us / stall ~40us; occupancy
// is pinned at 4 waves/SIMD for any VGPR in (64,128] (r19@108 and r23@92
// show identical occupancy -> coarse HW quantum), so the lever is
// per-stream dependent-latency, not residency.
// Changes vs r23 (leaf phase only):
//  1. REMOVE the inter-subtree sched_barrier: the two L9 table-chains
//     (gather->hadamard->hsum->rcp) are independent; the fence was
//     r17-era medicine when demand was 212. Now 92+~20 stays under the
//     128 cliff and the chains interleave. (matvec_bt fences KEPT.)
//  2. Hoist all 7 xs symbol bytes to one early back-to-back burst
//     (leaves@4p8+3..6, L9@2p8+1..2, L8@p8) -- one LDS latency, not 4.
//  3. Fuse leaf-phase logs: log(nua*nub*nu8), product >= ~1e-12 (nu in
//     [~1e-4,1]) -- 2 fewer transcendentals/thread. Tail NOT fused
//     (7-level product could hit 1e-28).
// Tripwires: VGPR>128 (occupancy ~10%) or WRITE_SIZE>>4KB => re-fence.
// Structure: 1024 independent blocks, one (t,g) each, no workspace/atomics.

#define C_DIM 16
#define M_DIM 64
#define G_DIM 16
#define T_TREES 64
#define N1 2047
#define NBLOCKS (T_TREES * G_DIM)   // 1024
#define BTS 20                      // padded row stride (floats) for xv-tables

__device__ __forceinline__ float4 f4add(float4 a, float4 b) {
    return make_float4(a.x + b.x, a.y + b.y, a.z + b.z, a.w + b.w);
}
__device__ __forceinline__ float4 f4mul(float4 a, float4 b) {
    return make_float4(a.x * b.x, a.y * b.y, a.z * b.z, a.w * b.w);
}
__device__ __forceinline__ float4 f4fma(float4 a, float4 b, float4 c) {
    return make_float4(fmaf(a.x, b.x, c.x), fmaf(a.y, b.y, c.y),
                       fmaf(a.z, b.z, c.z), fmaf(a.w, b.w, c.w));
}
__device__ __forceinline__ float hsum4(float4 a) { return a.x + a.y + a.z + a.w; }

// bp[q] = (A[4q+r]·s) * Bt[4q+r]; returns nu = sum(bp).
// Two 8-row halves with a hard sched fence between (r19-proven: caps
// in-flight ds_read_b128 liveness).
__device__ __forceinline__ float matvec_bt(const float* __restrict__ A,
                                           const float* __restrict__ bt,
                                           const float4 sv[4], float4 bp[4])
{
    float nu = 0.f;
    #pragma unroll
    for (int h = 0; h < 2; ++h) {
        #pragma unroll
        for (int q = 2 * h; q < 2 * h + 2; ++q) {
            const float4 b4 = *(const float4*)(bt + 4 * q);
            float tr[4];
            #pragma unroll
            for (int r = 0; r < 4; ++r) {
                const float4* ar = (const float4*)(A + (4 * q + r) * 16);
                float4 m = f4mul(ar[0], sv[0]);
                m = f4fma(ar[1], sv[1], m);
                m = f4fma(ar[2], sv[2], m);
                m = f4fma(ar[3], sv[3], m);
                tr[r] = hsum4(m);
            }
            bp[q] = f4mul(make_float4(tr[0], tr[1], tr[2], tr[3]), b4);
            nu += hsum4(bp[q]);
        }
        __builtin_amdgcn_sched_barrier(0);   // liveness fence: half-matvec
    }
    return nu;
}

__global__ __launch_bounds__(256, 1) void htmm_fused(
    const int* __restrict__ x,
    const int* __restrict__ inv_map,
    const float* __restrict__ lA,
    const float* __restrict__ lB,
    const float* __restrict__ lPi,
    float* __restrict__ out)
{
    const int bid = blockIdx.x;           // 1024 blocks: g = bid>>6, t = bid&63
    const int tid = threadIdx.x;
    const int g = bid >> 6;
    const int t = bid & (T_TREES - 1);

    // ---- manual LDS layout (r21 diet): 32768 B ----
    __shared__ __align__(16) unsigned char smem[32768];
    float* const sA   = (float*)(smem);            //     0 .. 1024   A row-major
    float* const sBt  = (float*)(smem + 1024);     //  1024 .. 6144   Bt[xv][c] stride 20
    float* const sPB  = (float*)(smem + 6144);     //  6144 .. 11264  tA[x]=A·PB[x] (leaf-phase only)
    float* const sLog = (float*)(smem + 11264);    // 11264 .. 11520  (dead after leaf)
    float* const sPi  = (float*)(smem + 11520);    // 11520 .. 11584  (dead after tables)
    float* const buf1 = (float*)(smem + 6144);     // UNION: live from L7 on (8192B)
    unsigned char* const xs = smem + 14336;        // 14336 .. 16384
    float* const buf0 = (float*)(smem + 16384);    // 16384 .. 32768
    float* const wsum = (float*)(smem + 32752);    // buf0 row15 col252-255 (tail-unused)

    // ---- tree symbols (coalesced; 16 same-tree blocks share L2) ----
    {
        const int base = t * N1;
        for (int i = tid; i < N1; i += 256)
            xs[i] = (unsigned char)x[inv_map[base + i]];
    }
    // ---- A softmax (over i within 16-lane segments) ----
    {
        int j = tid >> 4, i = tid & 15;
        float v = lA[(i * C_DIM + j) * G_DIM + g];
        float mx = v;
        #pragma unroll
        for (int m = 1; m < 16; m <<= 1) mx = fmaxf(mx, __shfl_xor(mx, m, 16));
        float e = __expf(v - mx);
        float s = e;
        #pragma unroll
        for (int m = 1; m < 16; m <<= 1) s += __shfl_xor(s, m, 16);
        sA[i * C_DIM + j] = e / s;
    }
    // ---- B softmax (over m), written TRANSPOSED: sBt[xv*BTS + c] ----
    {
        int c = tid >> 4, l16 = tid & 15;
        float e0 = lB[(c * M_DIM + l16 +  0) * G_DIM + g];
        float e1 = lB[(c * M_DIM + l16 + 16) * G_DIM + g];
        float e2 = lB[(c * M_DIM + l16 + 32) * G_DIM + g];
        float e3 = lB[(c * M_DIM + l16 + 48) * G_DIM + g];
        float mx = fmaxf(fmaxf(e0, e1), fmaxf(e2, e3));
        #pragma unroll
        for (int m = 1; m < 16; m <<= 1) mx = fmaxf(mx, __shfl_xor(mx, m, 16));
        e0 = __expf(e0 - mx); e1 = __expf(e1 - mx);
        e2 = __expf(e2 - mx); e3 = __expf(e3 - mx);
        float s = e0 + e1 + e2 + e3;
        #pragma unroll
        for (int m = 1; m < 16; m <<= 1) s += __shfl_xor(s, m, 16);
        float inv = 1.f / s;
        sBt[(l16 +  0) * BTS + c] = e0 * inv;
        sBt[(l16 + 16) * BTS + c] = e1 * inv;
        sBt[(l16 + 32) * BTS + c] = e2 * inv;
        sBt[(l16 + 48) * BTS + c] = e3 * inv;
    }
    if (tid < C_DIM) {  // Pi softmax
        float v = lPi[tid * G_DIM + g];
        float mx = v;
        #pragma unroll
        for (int m = 1; m < 16; m <<= 1) mx = fmaxf(mx, __shfl_xor(mx, m, 16));
        float e = __expf(v - mx);
        float s = e;
        #pragma unroll
        for (int m = 1; m < 16; m <<= 1) s += __shfl_xor(s, m, 16);
        sPi[tid] = e / s;
    }
    __syncthreads();

    // ---- leaf tables + LINEARITY fold: write tA[x] = A·PB[x] ----
    if (tid < M_DIM) {
        const int xv = tid;
        float pb[16]; float nu = 0.f;
        #pragma unroll
        for (int k = 0; k < 16; ++k) {
            pb[k] = sPi[k] * sBt[xv * BTS + k];
            nu += pb[k];
        }
        const float inv = 0.5f / nu;
        #pragma unroll
        for (int k = 0; k < 16; ++k) pb[k] *= inv;
        sLog[xv] = __logf(nu);
        const float4 pv0 = make_float4(pb[0],  pb[1],  pb[2],  pb[3]);
        const float4 pv1 = make_float4(pb[4],  pb[5],  pb[6],  pb[7]);
        const float4 pv2 = make_float4(pb[8],  pb[9],  pb[10], pb[11]);
        const float4 pv3 = make_float4(pb[12], pb[13], pb[14], pb[15]);
        float ta[16];
        #pragma unroll
        for (int i = 0; i < 16; ++i) {
            const float4* ar = (const float4*)(sA + i * 16);
            float4 m = f4mul(ar[0], pv0);
            m = f4fma(ar[1], pv1, m);
            m = f4fma(ar[2], pv2, m);
            m = f4fma(ar[3], pv3, m);
            ta[i] = hsum4(m);
            if ((i & 3) == 3) __builtin_amdgcn_sched_barrier(0);  // cap in-flight
        }
        #pragma unroll
        for (int q = 0; q < 4; ++q)
            *(float4*)(&sPB[xv * BTS + 4 * q]) =
                make_float4(ta[4*q], ta[4*q+1], ta[4*q+2], ta[4*q+3]);
    }
    __syncthreads();

    float ll = 0.f;

    // ---- fused leaves+L9 (TABLE, both subtrees INTERLEAVED) + L8 ----
    {
        const int idx = tid;
        const int p8  = 255 + idx;
        // all 7 symbols hoisted: one back-to-back LDS burst
        const int xl0 = xs[4 * p8 + 3], xr0 = xs[4 * p8 + 4];
        const int xl1 = xs[4 * p8 + 5], xr1 = xs[4 * p8 + 6];
        const int xva = xs[2 * p8 + 1], xvb = xs[2 * p8 + 2];
        const int xv8 = xs[p8];

        const float* tl0 = &sPB[xl0 * BTS];
        const float* tr0 = &sPB[xr0 * BTS];
        const float* tl1 = &sPB[xl1 * BTS];
        const float* tr1 = &sPB[xr1 * BTS];
        const float* bta = &sBt[xva * BTS];
        const float* btb = &sBt[xvb * BTS];

        float4 bpa[4], bpb[4];
        float nua = 0.f, nub = 0.f;
        #pragma unroll
        for (int q = 0; q < 4; ++q) {
            float4 tva = f4add(*(const float4*)(tl0 + 4*q),
                               *(const float4*)(tr0 + 4*q));
            float4 tvb = f4add(*(const float4*)(tl1 + 4*q),
                               *(const float4*)(tr1 + 4*q));
            bpa[q] = f4mul(tva, *(const float4*)(bta + 4*q));
            bpb[q] = f4mul(tvb, *(const float4*)(btb + 4*q));
            nua += hsum4(bpa[q]);
            nub += hsum4(bpb[q]);
        }
        const float ia = 0.5f / nua, ib = 0.5f / nub;
        float4 s8v[4];
        #pragma unroll
        for (int q = 0; q < 4; ++q)
            s8v[q] = f4add(f4mul(bpa[q], make_float4(ia, ia, ia, ia)),
                           f4mul(bpb[q], make_float4(ib, ib, ib, ib)));

        float4 bp[4];
        const float nu8 = matvec_bt(sA, &sBt[xv8 * BTS], s8v, bp);
        // fused log: nua,nub,nu8 each in [~1e-4,1] -> product >= ~1e-12
        ll += sLog[xl0] + sLog[xr0] + sLog[xl1] + sLog[xr1]
            + __logf(nua * nub * nu8);
        const float inv = 1.f / nu8;
        #pragma unroll
        for (int q = 0; q < 4; ++q) {
            buf0[(4*q + 0) * 256 + idx] = bp[q].x * inv;
            buf0[(4*q + 1) * 256 + idx] = bp[q].y * inv;
            buf0[(4*q + 2) * 256 + idx] = bp[q].z * inv;
            buf0[(4*q + 3) * 256 + idx] = bp[q].w * inv;
        }
    }
    __syncthreads();

    // ---- L7: 128 nodes (buf1 aliases the now-dead tA region) ----
    if (tid < 128) {
        const int idx = tid;
        float4 sv[4];
        #pragma unroll
        for (int q = 0; q < 4; ++q) {
            float2 c0 = *(const float2*)(&buf0[(4*q + 0) * 256 + 2 * idx]);
            float2 c1 = *(const float2*)(&buf0[(4*q + 1) * 256 + 2 * idx]);
            float2 c2 = *(const float2*)(&buf0[(4*q + 2) * 256 + 2 * idx]);
            float2 c3 = *(const float2*)(&buf0[(4*q + 3) * 256 + 2 * idx]);
            sv[q] = make_float4(0.5f * (c0.x + c0.y), 0.5f * (c1.x + c1.y),
                                0.5f * (c2.x + c2.y), 0.5f * (c3.x + c3.y));
        }
        const int xv = xs[127 + idx];
        float4 bp[4];
        float nu = matvec_bt(sA, &sBt[xv * BTS], sv, bp);
        ll += __logf(nu);
        const float inv = 1.f / nu;
        #pragma unroll
        for (int q = 0; q < 4; ++q) {
            buf1[(4*q + 0) * 128 + idx] = bp[q].x * inv;
            buf1[(4*q + 1) * 128 + idx] = bp[q].y * inv;
            buf1[(4*q + 2) * 128 + idx] = bp[q].z * inv;
            buf1[(4*q + 3) * 128 + idx] = bp[q].w * inv;
        }
    }
    __syncthreads();

    // ---- L6..L0 (64..1 nodes): wave 0 only, LDS fences not barriers ----
    if (tid < 64) {
        float* cur = buf1; int cs = 128;
        float* nxt = buf0; int ns = 256;
        for (int cnt2 = 64; cnt2 >= 1; cnt2 >>= 1) {
            if (tid < cnt2) {
                const int idx = tid;
                float4 sv[4];
                #pragma unroll
                for (int q = 0; q < 4; ++q) {
                    float2 c0 = *(const float2*)(&cur[(4*q + 0) * cs + 2 * idx]);
                    float2 c1 = *(const float2*)(&cur[(4*q + 1) * cs + 2 * idx]);
                    float2 c2 = *(const float2*)(&cur[(4*q + 2) * cs + 2 * idx]);
                    float2 c3 = *(const float2*)(&cur[(4*q + 3) * cs + 2 * idx]);
                    sv[q] = make_float4(0.5f * (c0.x + c0.y), 0.5f * (c1.x + c1.y),
                                        0.5f * (c2.x + c2.y), 0.5f * (c3.x + c3.y));
                }
                const int xv = xs[cnt2 - 1 + idx];
                float4 bp[4];
                float nu = matvec_bt(sA, &sBt[xv * BTS], sv, bp);
                ll += __logf(nu);
                const float inv = 1.f / nu;
                #pragma unroll
                for (int q = 0; q < 4; ++q) {
                    nxt[(4*q + 0) * ns + idx] = bp[q].x * inv;
                    nxt[(4*q + 1) * ns + idx] = bp[q].y * inv;
                    nxt[(4*q + 2) * ns + idx] = bp[q].z * inv;
                    nxt[(4*q + 3) * ns + idx] = bp[q].w * inv;
                }
            }
            asm volatile("s_waitcnt lgkmcnt(0)" ::: "memory");
            __builtin_amdgcn_wave_barrier();
            float* tp = cur; cur = nxt; nxt = tp;
            int ts = cs; cs = ns; ns = ts;
        }
    }

    // ---- reduce ll across block (wsum in buf0 row15 cols252-255) ----
    float v = ll;
    #pragma unroll
    for (int off = 32; off > 0; off >>= 1) v += __shfl_down(v, off, 64);
    if ((tid & 63) == 0) wsum[tid >> 6] = v;
    __syncthreads();
    if (tid == 0) out[t * G_DIM + g] = wsum[0] + wsum[1] + wsum[2] + wsum[3];
}

extern "C" void kernel_launch(void* const* d_in, const int* in_sizes, int n_in,
                              void* d_out, int out_size, void* d_ws, size_t ws_size,
                              hipStream_t stream) {
    const int*   x       = (const int*)d_in[0];
    const int*   inv_map = (const int*)d_in[6];
    const float* lA      = (const float*)d_in[7];
    const float* lB      = (const float*)d_in[8];
    const float* lPi     = (const float*)d_in[9];
    float* out = (float*)d_out;

    htmm_fused<<<dim3(NBLOCKS), dim3(256), 0, stream>>>(
        x, inv_map, lA, lB, lPi, out);
}

// Round 14
// 109.633 us; speedup vs baseline: 1.0602x; 1.0602x over previous
//
#include <hip/hip_runtime.h>

// UniformBottomUpHTMM: T=64 trees, depth 10 (N1=2047 heap), C=16, M=64,
// G=16. r25: tail hi/lo row-split. Corrected cost model: each matvec
// event issues 64 uniform ds_read_b128 for A (16 rows x 4); per block
// leaf 4x64 + L7 2x64 + TAIL 7x64=448 -> ~1000 LDS instr/block, x4
// blocks/CU x 12cy ~= 20us LDS-pipe in phase-locked bursts = the wall.
// The tail is the worst consumer (54% of A-traffic for 127/511 nodes,
// one wave, lanes 32-63 idle at cnt2<=32).
// Fix: for cnt2<=32, lanes n and n+32 both serve node n -- lane n rows
// 0-7, lane n+32 rows 8-15. Each A-read instruction now carries TWO
// addresses (2-way broadcast = conflict-free, free) -> 32 instr not 64;
// Bt 2 not 4; stores 8 not 16. nu combined via 2x shfl_xor(32) with
// summation re-associated to BIT-MATCH the original ((h0+h1)+h2)+h3
// order (absmax stays 0.0); log counted once (half==0). cnt2=64 level
// unchanged (no idle lanes). Leaf/L7 keep r24 form (pair-split there
// needs sv-exchange + register risk; deferred).
// Tripwires: VGPR>128 or WRITE_SIZE>>4KB => revert. absmax must stay 0.
// Structure: 1024 independent blocks, one (t,g) each, no workspace/atomics.

#define C_DIM 16
#define M_DIM 64
#define G_DIM 16
#define T_TREES 64
#define N1 2047
#define NBLOCKS (T_TREES * G_DIM)   // 1024
#define BTS 20                      // padded row stride (floats) for xv-tables

__device__ __forceinline__ float4 f4add(float4 a, float4 b) {
    return make_float4(a.x + b.x, a.y + b.y, a.z + b.z, a.w + b.w);
}
__device__ __forceinline__ float4 f4mul(float4 a, float4 b) {
    return make_float4(a.x * b.x, a.y * b.y, a.z * b.z, a.w * b.w);
}
__device__ __forceinline__ float4 f4fma(float4 a, float4 b, float4 c) {
    return make_float4(fmaf(a.x, b.x, c.x), fmaf(a.y, b.y, c.y),
                       fmaf(a.z, b.z, c.z), fmaf(a.w, b.w, c.w));
}
__device__ __forceinline__ float hsum4(float4 a) { return a.x + a.y + a.z + a.w; }

// bp[q] = (A[4q+r]·s) * Bt[4q+r]; returns nu = sum(bp).
// Two 8-row halves with a hard sched fence between (r19-proven).
__device__ __forceinline__ float matvec_bt(const float* __restrict__ A,
                                           const float* __restrict__ bt,
                                           const float4 sv[4], float4 bp[4])
{
    float nu = 0.f;
    #pragma unroll
    for (int h = 0; h < 2; ++h) {
        #pragma unroll
        for (int q = 2 * h; q < 2 * h + 2; ++q) {
            const float4 b4 = *(const float4*)(bt + 4 * q);
            float tr[4];
            #pragma unroll
            for (int r = 0; r < 4; ++r) {
                const float4* ar = (const float4*)(A + (4 * q + r) * 16);
                float4 m = f4mul(ar[0], sv[0]);
                m = f4fma(ar[1], sv[1], m);
                m = f4fma(ar[2], sv[2], m);
                m = f4fma(ar[3], sv[3], m);
                tr[r] = hsum4(m);
            }
            bp[q] = f4mul(make_float4(tr[0], tr[1], tr[2], tr[3]), b4);
            nu += hsum4(bp[q]);
        }
        __builtin_amdgcn_sched_barrier(0);   // liveness fence: half-matvec
    }
    return nu;
}

__global__ __launch_bounds__(256, 1) void htmm_fused(
    const int* __restrict__ x,
    const int* __restrict__ inv_map,
    const float* __restrict__ lA,
    const float* __restrict__ lB,
    const float* __restrict__ lPi,
    float* __restrict__ out)
{
    const int bid = blockIdx.x;           // 1024 blocks: g = bid>>6, t = bid&63
    const int tid = threadIdx.x;
    const int g = bid >> 6;
    const int t = bid & (T_TREES - 1);

    // ---- manual LDS layout (r21 diet): 32768 B ----
    __shared__ __align__(16) unsigned char smem[32768];
    float* const sA   = (float*)(smem);            //     0 .. 1024   A row-major
    float* const sBt  = (float*)(smem + 1024);     //  1024 .. 6144   Bt[xv][c] stride 20
    float* const sPB  = (float*)(smem + 6144);     //  6144 .. 11264  tA[x]=A·PB[x] (leaf-phase only)
    float* const sLog = (float*)(smem + 11264);    // 11264 .. 11520  (dead after leaf)
    float* const sPi  = (float*)(smem + 11520);    // 11520 .. 11584  (dead after tables)
    float* const buf1 = (float*)(smem + 6144);     // UNION: live from L7 on (8192B)
    unsigned char* const xs = smem + 14336;        // 14336 .. 16384
    float* const buf0 = (float*)(smem + 16384);    // 16384 .. 32768
    float* const wsum = (float*)(smem + 32752);    // buf0 row15 col252-255 (tail-unused)

    // ---- tree symbols (coalesced; 16 same-tree blocks share L2) ----
    {
        const int base = t * N1;
        for (int i = tid; i < N1; i += 256)
            xs[i] = (unsigned char)x[inv_map[base + i]];
    }
    // ---- A softmax (over i within 16-lane segments) ----
    {
        int j = tid >> 4, i = tid & 15;
        float v = lA[(i * C_DIM + j) * G_DIM + g];
        float mx = v;
        #pragma unroll
        for (int m = 1; m < 16; m <<= 1) mx = fmaxf(mx, __shfl_xor(mx, m, 16));
        float e = __expf(v - mx);
        float s = e;
        #pragma unroll
        for (int m = 1; m < 16; m <<= 1) s += __shfl_xor(s, m, 16);
        sA[i * C_DIM + j] = e / s;
    }
    // ---- B softmax (over m), written TRANSPOSED: sBt[xv*BTS + c] ----
    {
        int c = tid >> 4, l16 = tid & 15;
        float e0 = lB[(c * M_DIM + l16 +  0) * G_DIM + g];
        float e1 = lB[(c * M_DIM + l16 + 16) * G_DIM + g];
        float e2 = lB[(c * M_DIM + l16 + 32) * G_DIM + g];
        float e3 = lB[(c * M_DIM + l16 + 48) * G_DIM + g];
        float mx = fmaxf(fmaxf(e0, e1), fmaxf(e2, e3));
        #pragma unroll
        for (int m = 1; m < 16; m <<= 1) mx = fmaxf(mx, __shfl_xor(mx, m, 16));
        e0 = __expf(e0 - mx); e1 = __expf(e1 - mx);
        e2 = __expf(e2 - mx); e3 = __expf(e3 - mx);
        float s = e0 + e1 + e2 + e3;
        #pragma unroll
        for (int m = 1; m < 16; m <<= 1) s += __shfl_xor(s, m, 16);
        float inv = 1.f / s;
        sBt[(l16 +  0) * BTS + c] = e0 * inv;
        sBt[(l16 + 16) * BTS + c] = e1 * inv;
        sBt[(l16 + 32) * BTS + c] = e2 * inv;
        sBt[(l16 + 48) * BTS + c] = e3 * inv;
    }
    if (tid < C_DIM) {  // Pi softmax
        float v = lPi[tid * G_DIM + g];
        float mx = v;
        #pragma unroll
        for (int m = 1; m < 16; m <<= 1) mx = fmaxf(mx, __shfl_xor(mx, m, 16));
        float e = __expf(v - mx);
        float s = e;
        #pragma unroll
        for (int m = 1; m < 16; m <<= 1) s += __shfl_xor(s, m, 16);
        sPi[tid] = e / s;
    }
    __syncthreads();

    // ---- leaf tables + LINEARITY fold: write tA[x] = A·PB[x] ----
    if (tid < M_DIM) {
        const int xv = tid;
        float pb[16]; float nu = 0.f;
        #pragma unroll
        for (int k = 0; k < 16; ++k) {
            pb[k] = sPi[k] * sBt[xv * BTS + k];
            nu += pb[k];
        }
        const float inv = 0.5f / nu;
        #pragma unroll
        for (int k = 0; k < 16; ++k) pb[k] *= inv;
        sLog[xv] = __logf(nu);
        const float4 pv0 = make_float4(pb[0],  pb[1],  pb[2],  pb[3]);
        const float4 pv1 = make_float4(pb[4],  pb[5],  pb[6],  pb[7]);
        const float4 pv2 = make_float4(pb[8],  pb[9],  pb[10], pb[11]);
        const float4 pv3 = make_float4(pb[12], pb[13], pb[14], pb[15]);
        float ta[16];
        #pragma unroll
        for (int i = 0; i < 16; ++i) {
            const float4* ar = (const float4*)(sA + i * 16);
            float4 m = f4mul(ar[0], pv0);
            m = f4fma(ar[1], pv1, m);
            m = f4fma(ar[2], pv2, m);
            m = f4fma(ar[3], pv3, m);
            ta[i] = hsum4(m);
            if ((i & 3) == 3) __builtin_amdgcn_sched_barrier(0);  // cap in-flight
        }
        #pragma unroll
        for (int q = 0; q < 4; ++q)
            *(float4*)(&sPB[xv * BTS + 4 * q]) =
                make_float4(ta[4*q], ta[4*q+1], ta[4*q+2], ta[4*q+3]);
    }
    __syncthreads();

    float ll = 0.f;

    // ---- fused leaves+L9 (TABLE, both subtrees interleaved) + L8 ----
    {
        const int idx = tid;
        const int p8  = 255 + idx;
        const int xl0 = xs[4 * p8 + 3], xr0 = xs[4 * p8 + 4];
        const int xl1 = xs[4 * p8 + 5], xr1 = xs[4 * p8 + 6];
        const int xva = xs[2 * p8 + 1], xvb = xs[2 * p8 + 2];
        const int xv8 = xs[p8];

        const float* tl0 = &sPB[xl0 * BTS];
        const float* tr0 = &sPB[xr0 * BTS];
        const float* tl1 = &sPB[xl1 * BTS];
        const float* tr1 = &sPB[xr1 * BTS];
        const float* bta = &sBt[xva * BTS];
        const float* btb = &sBt[xvb * BTS];

        float4 bpa[4], bpb[4];
        float nua = 0.f, nub = 0.f;
        #pragma unroll
        for (int q = 0; q < 4; ++q) {
            float4 tva = f4add(*(const float4*)(tl0 + 4*q),
                               *(const float4*)(tr0 + 4*q));
            float4 tvb = f4add(*(const float4*)(tl1 + 4*q),
                               *(const float4*)(tr1 + 4*q));
            bpa[q] = f4mul(tva, *(const float4*)(bta + 4*q));
            bpb[q] = f4mul(tvb, *(const float4*)(btb + 4*q));
            nua += hsum4(bpa[q]);
            nub += hsum4(bpb[q]);
        }
        const float ia = 0.5f / nua, ib = 0.5f / nub;
        float4 s8v[4];
        #pragma unroll
        for (int q = 0; q < 4; ++q)
            s8v[q] = f4add(f4mul(bpa[q], make_float4(ia, ia, ia, ia)),
                           f4mul(bpb[q], make_float4(ib, ib, ib, ib)));

        float4 bp[4];
        const float nu8 = matvec_bt(sA, &sBt[xv8 * BTS], s8v, bp);
        ll += sLog[xl0] + sLog[xr0] + sLog[xl1] + sLog[xr1]
            + __logf(nua * nub * nu8);
        const float inv = 1.f / nu8;
        #pragma unroll
        for (int q = 0; q < 4; ++q) {
            buf0[(4*q + 0) * 256 + idx] = bp[q].x * inv;
            buf0[(4*q + 1) * 256 + idx] = bp[q].y * inv;
            buf0[(4*q + 2) * 256 + idx] = bp[q].z * inv;
            buf0[(4*q + 3) * 256 + idx] = bp[q].w * inv;
        }
    }
    __syncthreads();

    // ---- L7: 128 nodes (buf1 aliases the now-dead tA region) ----
    if (tid < 128) {
        const int idx = tid;
        float4 sv[4];
        #pragma unroll
        for (int q = 0; q < 4; ++q) {
            float2 c0 = *(const float2*)(&buf0[(4*q + 0) * 256 + 2 * idx]);
            float2 c1 = *(const float2*)(&buf0[(4*q + 1) * 256 + 2 * idx]);
            float2 c2 = *(const float2*)(&buf0[(4*q + 2) * 256 + 2 * idx]);
            float2 c3 = *(const float2*)(&buf0[(4*q + 3) * 256 + 2 * idx]);
            sv[q] = make_float4(0.5f * (c0.x + c0.y), 0.5f * (c1.x + c1.y),
                                0.5f * (c2.x + c2.y), 0.5f * (c3.x + c3.y));
        }
        const int xv = xs[127 + idx];
        float4 bp[4];
        float nu = matvec_bt(sA, &sBt[xv * BTS], sv, bp);
        ll += __logf(nu);
        const float inv = 1.f / nu;
        #pragma unroll
        for (int q = 0; q < 4; ++q) {
            buf1[(4*q + 0) * 128 + idx] = bp[q].x * inv;
            buf1[(4*q + 1) * 128 + idx] = bp[q].y * inv;
            buf1[(4*q + 2) * 128 + idx] = bp[q].z * inv;
            buf1[(4*q + 3) * 128 + idx] = bp[q].w * inv;
        }
    }
    __syncthreads();

    // ---- tail: wave 0 only ----
    if (tid < 64) {
        float* cur = buf1; int cs = 128;
        float* nxt = buf0; int ns = 256;

        // L6 (cnt2=64): full-width, all 64 lanes, unchanged
        {
            const int idx = tid;
            float4 sv[4];
            #pragma unroll
            for (int q = 0; q < 4; ++q) {
                float2 c0 = *(const float2*)(&cur[(4*q + 0) * cs + 2 * idx]);
                float2 c1 = *(const float2*)(&cur[(4*q + 1) * cs + 2 * idx]);
                float2 c2 = *(const float2*)(&cur[(4*q + 2) * cs + 2 * idx]);
                float2 c3 = *(const float2*)(&cur[(4*q + 3) * cs + 2 * idx]);
                sv[q] = make_float4(0.5f * (c0.x + c0.y), 0.5f * (c1.x + c1.y),
                                    0.5f * (c2.x + c2.y), 0.5f * (c3.x + c3.y));
            }
            const int xv = xs[63 + idx];
            float4 bp[4];
            float nu = matvec_bt(sA, &sBt[xv * BTS], sv, bp);
            ll += __logf(nu);
            const float inv = 1.f / nu;
            #pragma unroll
            for (int q = 0; q < 4; ++q) {
                nxt[(4*q + 0) * ns + idx] = bp[q].x * inv;
                nxt[(4*q + 1) * ns + idx] = bp[q].y * inv;
                nxt[(4*q + 2) * ns + idx] = bp[q].z * inv;
                nxt[(4*q + 3) * ns + idx] = bp[q].w * inv;
            }
            asm volatile("s_waitcnt lgkmcnt(0)" ::: "memory");
            __builtin_amdgcn_wave_barrier();
            float* tp = cur; cur = nxt; nxt = tp;
            int ts = cs; cs = ns; ns = ts;
        }

        // L5..L0 (cnt2=32..1): hi/lo row-split. Lane n (lo) rows 0-7,
        // lane n+32 (hi) rows 8-15 of node n. A-reads become 2-address
        // broadcasts (free): 32 instr/level not 64. nu re-associated to
        // bit-match the original ((h0+h1)+h2)+h3.
        for (int cnt2 = 32; cnt2 >= 1; cnt2 >>= 1) {
            const int half = tid >> 5;        // 0: rows 0-7, 1: rows 8-15
            const int n    = tid & 31;        // node index
            if (n < cnt2) {
                float4 sv[4];
                #pragma unroll
                for (int q = 0; q < 4; ++q) {
                    float2 c0 = *(const float2*)(&cur[(4*q + 0) * cs + 2 * n]);
                    float2 c1 = *(const float2*)(&cur[(4*q + 1) * cs + 2 * n]);
                    float2 c2 = *(const float2*)(&cur[(4*q + 2) * cs + 2 * n]);
                    float2 c3 = *(const float2*)(&cur[(4*q + 3) * cs + 2 * n]);
                    sv[q] = make_float4(0.5f * (c0.x + c0.y), 0.5f * (c1.x + c1.y),
                                        0.5f * (c2.x + c2.y), 0.5f * (c3.x + c3.y));
                }
                const int xv = xs[cnt2 - 1 + n];
                const float* bt = &sBt[xv * BTS];
                const int r0 = half * 8;      // my first row

                float4 bpA; float hA;         // rows r0..r0+3
                {
                    float tr[4];
                    #pragma unroll
                    for (int r = 0; r < 4; ++r) {
                        const float4* ar = (const float4*)(sA + (r0 + r) * 16);
                        float4 m = f4mul(ar[0], sv[0]);
                        m = f4fma(ar[1], sv[1], m);
                        m = f4fma(ar[2], sv[2], m);
                        m = f4fma(ar[3], sv[3], m);
                        tr[r] = hsum4(m);
                    }
                    bpA = f4mul(make_float4(tr[0], tr[1], tr[2], tr[3]),
                                *(const float4*)(bt + r0));
                    hA = hsum4(bpA);
                }
                __builtin_amdgcn_sched_barrier(0);
                float4 bpB; float hB;         // rows r0+4..r0+7
                {
                    float tr[4];
                    #pragma unroll
                    for (int r = 0; r < 4; ++r) {
                        const float4* ar = (const float4*)(sA + (r0 + 4 + r) * 16);
                        float4 m = f4mul(ar[0], sv[0]);
                        m = f4fma(ar[1], sv[1], m);
                        m = f4fma(ar[2], sv[2], m);
                        m = f4fma(ar[3], sv[3], m);
                        tr[r] = hsum4(m);
                    }
                    bpB = f4mul(make_float4(tr[0], tr[1], tr[2], tr[3]),
                                *(const float4*)(bt + r0 + 4));
                    hB = hsum4(bpB);
                }
                __builtin_amdgcn_sched_barrier(0);

                const float pA = __shfl_xor(hA, 32, 64);  // partner h-pair
                const float pB = __shfl_xor(hB, 32, 64);
                // lo holds (h0,h1), hi holds (h2,h3); both form ((h0+h1)+h2)+h3
                const float nu = half ? (((pA + pB) + hA) + hB)
                                      : (((hA + hB) + pA) + pB);
                if (half == 0) ll += __logf(nu);          // count once
                const float inv = 1.f / nu;
                nxt[(r0 + 0) * ns + n] = bpA.x * inv;
                nxt[(r0 + 1) * ns + n] = bpA.y * inv;
                nxt[(r0 + 2) * ns + n] = bpA.z * inv;
                nxt[(r0 + 3) * ns + n] = bpA.w * inv;
                nxt[(r0 + 4) * ns + n] = bpB.x * inv;
                nxt[(r0 + 5) * ns + n] = bpB.y * inv;
                nxt[(r0 + 6) * ns + n] = bpB.z * inv;
                nxt[(r0 + 7) * ns + n] = bpB.w * inv;
            }
            asm volatile("s_waitcnt lgkmcnt(0)" ::: "memory");
            __builtin_amdgcn_wave_barrier();
            float* tp = cur; cur = nxt; nxt = tp;
            int ts = cs; cs = ns; ns = ts;
        }
    }

    // ---- reduce ll across block (wsum in buf0 row15 cols252-255) ----
    float v = ll;
    #pragma unroll
    for (int off = 32; off > 0; off >>= 1) v += __shfl_down(v, off, 64);
    if ((tid & 63) == 0) wsum[tid >> 6] = v;
    __syncthreads();
    if (tid == 0) out[t * G_DIM + g] = wsum[0] + wsum[1] + wsum[2] + wsum[3];
}

extern "C" void kernel_launch(void* const* d_in, const int* in_sizes, int n_in,
                              void* d_out, int out_size, void* d_ws, size_t ws_size,
                              hipStream_t stream) {
    const int*   x       = (const int*)d_in[0];
    const int*   inv_map = (const int*)d_in[6];
    const float* lA      = (const float*)d_in[7];
    const float* lB      = (const float*)d_in[8];
    const float* lPi     = (const float*)d_in[9];
    float* out = (float*)d_out;

    htmm_fused<<<dim3(NBLOCKS), dim3(256), 0, stream>>>(
        x, inv_map, lA, lB, lPi, out);
}